// Round 5
// baseline (271.027 us; speedup 1.0000x reference)
//
#include <hip/hip_runtime.h>

#define HID 256
#define NB 8
#define SQL 2048
#define SKV 2048
#define SPLIT 2
#define KPB (SKV / SPLIT)   // 1024 keys per (b,s) stream
#define KVB 32              // keys per step
#define NT (KPB / KVB)      // 32 steps
#define NROW (NB * SQL)     // 16384 rows

typedef __attribute__((ext_vector_type(8))) short bf16x8;
typedef __attribute__((ext_vector_type(4))) float f32x4;

static __device__ __forceinline__ unsigned short f2bf(float x) {
  union { float f; unsigned int u; } v; v.f = x;
  unsigned int r = v.u + 0x7FFFu + ((v.u >> 16) & 1u);
  return (unsigned short)(r >> 16);
}

// ---------- P0: convert weight matrices to bf16 ----------
__global__ void wconv_kernel(const float* __restrict__ Wq, const float* __restrict__ Wk,
                             const float* __restrict__ Wv, unsigned short* __restrict__ out) {
  int i = blockIdx.x * blockDim.x + threadIdx.x;
  if (i >= 3 * HID * HID) return;
  const float* src = (i < HID * HID) ? Wq : (i < 2 * HID * HID ? Wk : Wv);
  out[i] = f2bf(src[i & (HID * HID - 1)]);
}

// ---------- P1: QKV projection; W-half staged in LDS (swizzled) ----------
__global__ __launch_bounds__(512, 4) void proj_kernel(
    const float* __restrict__ query, const float* __restrict__ key, const float* __restrict__ value,
    const unsigned short* __restrict__ Wb,
    const float* __restrict__ bq, const float* __restrict__ bk, const float* __restrict__ bv,
    unsigned short* __restrict__ Qb, unsigned short* __restrict__ Kb, unsigned short* __restrict__ Vtb) {
  __shared__ __align__(16) char wl[65536];
  int tid = threadIdx.x;
  int wave = tid >> 6, lane = tid & 63, lr = lane & 15, lg = lane >> 4;
  int blk = blockIdx.x;
  int mat = blk >> 8;       // 0:Q 1:K 2:V
  int rem = blk & 255;
  int b = rem >> 5;
  int rt = (rem >> 1) & 15;
  int et = rem & 1;

  const float* X = (mat == 0) ? query : (mat == 1 ? key : value);
  const float* bias = (mat == 0) ? bq : (mat == 1 ? bk : bv);
  const char* Wsrc = (const char*)(Wb + mat * HID * HID + et * 128 * HID);

#pragma unroll
  for (int i = 0; i < 8; i++) {
    int c = i * 512 + tid;
    int e = c >> 5;
    int glo = e * 512 + (((c & 31) ^ (e & 7)) << 4);
    __builtin_amdgcn_global_load_lds(
        (const __attribute__((address_space(1))) unsigned int*)(Wsrc + glo),
        (__attribute__((address_space(3))) unsigned int*)(wl + c * 16), 16, 0, 0);
  }

  int row_a = rt * 128 + wave * 16 + lr;
  const float* xrow = X + ((size_t)(b * SQL + row_a)) * HID;
  bf16x8 af[8];
#pragma unroll
  for (int s = 0; s < 8; s++) {
    const float4* p = (const float4*)(xrow + s * 32 + lg * 8);
    float4 x0 = p[0], x1 = p[1];
    bf16x8 a;
    a[0] = (short)f2bf(x0.x); a[1] = (short)f2bf(x0.y); a[2] = (short)f2bf(x0.z); a[3] = (short)f2bf(x0.w);
    a[4] = (short)f2bf(x1.x); a[5] = (short)f2bf(x1.y); a[6] = (short)f2bf(x1.z); a[7] = (short)f2bf(x1.w);
    af[s] = a;
  }
  __syncthreads();

  int row_c = rt * 128 + wave * 16 + lg * 4;
#pragma unroll
  for (int eo = 0; eo < 8; eo++) {
    f32x4 acc = (f32x4){0.f, 0.f, 0.f, 0.f};
    int eL = eo * 16 + lr;
#pragma unroll
    for (int sl = 0; sl < 8; sl++) {
      bf16x8 bfr = *(const bf16x8*)(wl + eL * 512 + (((sl * 4 + lg) ^ (eL & 7)) << 4));
      acc = __builtin_amdgcn_mfma_f32_16x16x32_bf16(af[sl], bfr, acc, 0, 0, 0);
    }
    int e = et * 128 + eo * 16 + lr;
    float bv_ = bias[e];
    if (mat < 2) {
      unsigned short* dst = (mat == 0 ? Qb : Kb) + (size_t)(b * SQL) * HID;
#pragma unroll
      for (int i = 0; i < 4; i++)
        dst[(size_t)(row_c + i) * HID + e] = f2bf(acc[i] + bv_);
    } else {
      ushort4 v;
      v.x = f2bf(acc[0] + bv_); v.y = f2bf(acc[1] + bv_);
      v.z = f2bf(acc[2] + bv_); v.w = f2bf(acc[3] + bv_);
      *(ushort4*)(Vtb + ((size_t)(b * HID + e)) * SKV + row_c) = v;
    }
  }
}

// ---------- A: flash attention, per-wave register streaming, no block barriers ----------
__global__ __launch_bounds__(256, 2) void attn_kernel(
    const unsigned short* __restrict__ Qb, const unsigned short* __restrict__ Kb,
    const unsigned short* __restrict__ Vtb, unsigned short* __restrict__ Op,
    float* __restrict__ Ml) {
  __shared__ __align__(16) char PB[4][1024];  // per-wave P bounce buffer
  int tid = threadIdx.x;
  int wave = tid >> 6, lane = tid & 63, l15 = lane & 15, g = lane >> 4;
  // XCD grouping: all 32 blocks of one (b,s) stream land on one XCD's L2
  int j = blockIdx.x;
  int p_ = (j & 7) + ((j >> 8) & 1) * 8;   // (b,s) pair 0..15
  int i_ = (j >> 3) & 31;                  // q-block within pair
  int b = p_ >> 1, s = p_ & 1;
  int q0 = (i_ * 4 + wave) * 16;

  const unsigned short* Kbase = Kb + ((size_t)b * SKV + (size_t)s * KPB) * HID;
  const unsigned short* Vbase = Vtb + (size_t)b * HID * SKV + (size_t)s * KPB;

  // Q fragments (B-operand): lane(col=q=l15, g) holds Q[q][sl*32 + g*8 ..+7]
  bf16x8 qf[8];
  {
    const unsigned short* qrow = Qb + ((size_t)(b * SQL + q0 + l15)) * HID + g * 8;
#pragma unroll
    for (int sl = 0; sl < 8; sl++) qf[sl] = *(const bf16x8*)(qrow + sl * 32);
  }

  f32x4 acc[16];
#pragma unroll
  for (int dt = 0; dt < 16; dt++) acc[dt] = (f32x4){0.f, 0.f, 0.f, 0.f};
  float m = -1e30f, lsum = 0.f;
  const float kC = 1.44269504088896341f / 11.3137084989847604f;  // log2(e)/sqrt(128)
  char* pb = PB[wave];

  for (int t = 0; t < NT; t++) {
    __builtin_amdgcn_s_barrier();  // rendezvous only (no drain): keep waves on same K/V tile
    int k0 = t * KVB;
    const unsigned short* Kt = Kbase + (size_t)k0 * HID;

    // K A-frags: lane(row=key=l15, g) holds K[key][sl*32 + g*8 ..+7]
    bf16x8 kf0[8], kf1[8];
#pragma unroll
    for (int sl = 0; sl < 8; sl++) {
      kf0[sl] = *(const bf16x8*)(Kt + (size_t)l15 * HID + sl * 32 + g * 8);
      kf1[sl] = *(const bf16x8*)(Kt + (size_t)(16 + l15) * HID + sl * 32 + g * 8);
    }
    // QK^T swapped: C[row=key][col=q]
    f32x4 p0 = (f32x4){0.f, 0.f, 0.f, 0.f}, p1 = (f32x4){0.f, 0.f, 0.f, 0.f};
#pragma unroll
    for (int sl = 0; sl < 8; sl++) {
      p0 = __builtin_amdgcn_mfma_f32_16x16x32_bf16(kf0[sl], qf[sl], p0, 0, 0, 0);
      p1 = __builtin_amdgcn_mfma_f32_16x16x32_bf16(kf1[sl], qf[sl], p1, 0, 0, 0);
    }

    // V B-frags: lane(col=d=l15, g) holds V[k0+g*8 ..+7][dt*16+l15] via Vt rows
    bf16x8 vf[16];
#pragma unroll
    for (int dt = 0; dt < 16; dt++)
      vf[dt] = *(const bf16x8*)(Vbase + (size_t)(dt * 16 + l15) * SKV + k0 + g * 8);

    // online softmax for q=l15 over this tile's 32 keys (8 in-lane + groups via shfl)
    float tmax = fmaxf(fmaxf(fmaxf(p0[0], p0[1]), fmaxf(p0[2], p0[3])),
                       fmaxf(fmaxf(p1[0], p1[1]), fmaxf(p1[2], p1[3])));
    tmax = fmaxf(tmax, __shfl_xor(tmax, 16, 64));
    tmax = fmaxf(tmax, __shfl_xor(tmax, 32, 64));
    float msc = tmax * kC;
    if (!__all(msc <= m + 8.0f)) {
      float mn = fmaxf(m, msc);
      float al = exp2f(m - mn);
      lsum *= al;
      m = mn;
#pragma unroll
      for (int i = 0; i < 4; i++) {
        float ar = __shfl(al, g * 4 + i, 64);  // acc rows are q = g*4+i
#pragma unroll
        for (int dt = 0; dt < 16; dt++) acc[dt][i] *= ar;
      }
    }
#pragma unroll
    for (int i = 0; i < 4; i++) {
      p0[i] = exp2f(fmaf(p0[i], kC, -m));
      p1[i] = exp2f(fmaf(p1[i], kC, -m));
    }
    float ts = (p0[0] + p0[1]) + (p0[2] + p0[3]) + (p1[0] + p1[1]) + (p1[2] + p1[3]);
    ts += __shfl_xor(ts, 16, 64);
    ts += __shfl_xor(ts, 32, 64);
    lsum += ts;

    // P C-layout -> A-frag via tiny per-wave LDS bounce (conflict-free, same-wave)
    unsigned u0, u1, u2, u3;
    asm("v_cvt_pk_bf16_f32 %0, %1, %2" : "=v"(u0) : "v"(p0[0]), "v"(p0[1]));
    asm("v_cvt_pk_bf16_f32 %0, %1, %2" : "=v"(u1) : "v"(p0[2]), "v"(p0[3]));
    asm("v_cvt_pk_bf16_f32 %0, %1, %2" : "=v"(u2) : "v"(p1[0]), "v"(p1[1]));
    asm("v_cvt_pk_bf16_f32 %0, %1, %2" : "=v"(u3) : "v"(p1[2]), "v"(p1[3]));
    uint2 w0; w0.x = u0; w0.y = u1;   // keys g*4..g*4+3 for q=l15
    uint2 w1; w1.x = u2; w1.y = u3;   // keys 16+g*4..+3
    *(uint2*)(pb + l15 * 64 + g * 8) = w0;
    *(uint2*)(pb + l15 * 64 + 32 + g * 8) = w1;
    bf16x8 pa = *(const bf16x8*)(pb + l15 * 64 + g * 16);  // A[row=q=l15][k=g*8..+7]

    // PV: 16 d-tiles, k=32 in one MFMA each
#pragma unroll
    for (int dt = 0; dt < 16; dt++)
      acc[dt] = __builtin_amdgcn_mfma_f32_16x16x32_bf16(pa, vf[dt], acc[dt], 0, 0, 0);
  }

  // epilogue
  if (g == 0) {
    float2 ml; ml.x = m; ml.y = lsum;
    *(float2*)(Ml + ((size_t)s * NROW + (size_t)b * SQL + q0 + l15) * 2) = ml;
  }
#pragma unroll
  for (int i = 0; i < 4; i++) {
    int q = g * 4 + i;
    float linv = 1.0f / __shfl(lsum, q, 64);
    size_t row = (size_t)b * SQL + q0 + q;
#pragma unroll
    for (int dt = 0; dt < 16; dt++) {
      union { _Float16 hf; unsigned short u; } cv;
      cv.hf = (_Float16)(acc[dt][i] * linv);
      Op[((size_t)s * NROW + row) * HID + dt * 16 + l15] = cv.u;
    }
  }
}

// ---------- C: combine split partials ----------
__global__ __launch_bounds__(256) void comb_kernel(const unsigned short* __restrict__ Op,
                                                   const float* __restrict__ Ml,
                                                   float* __restrict__ out) {
  int idx = blockIdx.x * 256 + threadIdx.x;
  int row = idx >> 6;
  int d0 = (idx & 63) << 2;
  float mv[SPLIT], lv[SPLIT];
#pragma unroll
  for (int s = 0; s < SPLIT; s++) {
    float2 ml = *(const float2*)(Ml + ((size_t)s * NROW + row) * 2);
    mv[s] = ml.x; lv[s] = ml.y;
  }
  float M = mv[0];
#pragma unroll
  for (int s = 1; s < SPLIT; s++) M = fmaxf(M, mv[s]);
  float W = 0.f, w[SPLIT];
#pragma unroll
  for (int s = 0; s < SPLIT; s++) { w[s] = lv[s] * exp2f(mv[s] - M); W += w[s]; }
  float wi = 1.0f / W;
  float o0 = 0.f, o1 = 0.f, o2 = 0.f, o3 = 0.f;
#pragma unroll
  for (int s = 0; s < SPLIT; s++) {
    ushort4 u = *(const ushort4*)(Op + ((size_t)s * NROW + row) * HID + d0);
    union { unsigned short us; _Float16 hf; } c0, c1, c2, c3;
    c0.us = u.x; c1.us = u.y; c2.us = u.z; c3.us = u.w;
    o0 += w[s] * (float)c0.hf; o1 += w[s] * (float)c1.hf;
    o2 += w[s] * (float)c2.hf; o3 += w[s] * (float)c3.hf;
  }
  float4 res; res.x = o0 * wi; res.y = o1 * wi; res.z = o2 * wi; res.w = o3 * wi;
  *(float4*)(out + (size_t)row * HID + d0) = res;
}

extern "C" void kernel_launch(void* const* d_in, const int* in_sizes, int n_in,
                              void* d_out, int out_size, void* d_ws, size_t ws_size,
                              hipStream_t stream) {
  const float* query = (const float*)d_in[0];
  const float* key   = (const float*)d_in[1];
  const float* value = (const float*)d_in[2];
  const float* Wq = (const float*)d_in[3];
  const float* bq = (const float*)d_in[4];
  const float* Wk = (const float*)d_in[5];
  const float* bk = (const float*)d_in[6];
  const float* Wv = (const float*)d_in[7];
  const float* bv = (const float*)d_in[8];

  char* ws = (char*)d_ws;
  unsigned short* Wb  = (unsigned short*)ws;                        // 393216 B
  unsigned short* Qb  = (unsigned short*)(ws + 393216);
  unsigned short* Kb  = Qb + (size_t)NB * SQL * HID;
  unsigned short* Vtb = Kb + (size_t)NB * SKV * HID;                // [b][d][s]
  unsigned short* Op  = Vtb + (size_t)NB * HID * SKV;               // f16 partials
  float* Ml = (float*)(Op + (size_t)SPLIT * NROW * HID);            // (m,l)

  hipLaunchKernelGGL(wconv_kernel, dim3(768), dim3(256), 0, stream, Wq, Wk, Wv, Wb);
  hipLaunchKernelGGL(proj_kernel, dim3(768), dim3(512), 0, stream,
                     query, key, value, Wb, bq, bk, bv, Qb, Kb, Vtb);
  hipLaunchKernelGGL(attn_kernel, dim3(512), dim3(256), 0, stream, Qb, Kb, Vtb, Op, Ml);
  hipLaunchKernelGGL(comb_kernel, dim3(4096), dim3(256), 0, stream, Op, Ml, (float*)d_out);
}

// Round 6
// 103.072 us; speedup vs baseline: 2.6295x; 2.6295x over previous
//
#include <hip/hip_runtime.h>

#define HID 256
#define NB 8
#define SQL 2048
#define SKV 2048
#define SPLIT 4
#define KPB (SKV / SPLIT)   // 512 keys per (b,s) stream
#define KVB 64              // keys per staged tile
#define NT (KPB / KVB)      // 8 staged steps
#define NROW (NB * SQL)     // 16384 rows

typedef __attribute__((ext_vector_type(8))) short bf16x8;
typedef __attribute__((ext_vector_type(4))) float f32x4;
typedef __attribute__((ext_vector_type(16))) float f32x16;

static __device__ __forceinline__ unsigned short f2bf(float x) {
  union { float f; unsigned int u; } v; v.f = x;
  unsigned int r = v.u + 0x7FFFu + ((v.u >> 16) & 1u);
  return (unsigned short)(r >> 16);
}

// ---------- P0: convert weight matrices to bf16 ----------
__global__ void wconv_kernel(const float* __restrict__ Wq, const float* __restrict__ Wk,
                             const float* __restrict__ Wv, unsigned short* __restrict__ out) {
  int i = blockIdx.x * blockDim.x + threadIdx.x;
  if (i >= 3 * HID * HID) return;
  const float* src = (i < HID * HID) ? Wq : (i < 2 * HID * HID ? Wk : Wv);
  out[i] = f2bf(src[i & (HID * HID - 1)]);
}

// ---------- P1: QKV projection; W-half staged in LDS (swizzled) ----------
__global__ __launch_bounds__(512, 4) void proj_kernel(
    const float* __restrict__ query, const float* __restrict__ key, const float* __restrict__ value,
    const unsigned short* __restrict__ Wb,
    const float* __restrict__ bq, const float* __restrict__ bk, const float* __restrict__ bv,
    unsigned short* __restrict__ Qb, unsigned short* __restrict__ Kb, unsigned short* __restrict__ Vtb) {
  __shared__ __align__(16) char wl[65536];
  int tid = threadIdx.x;
  int wave = tid >> 6, lane = tid & 63, lr = lane & 15, lg = lane >> 4;
  int blk = blockIdx.x;
  int mat = blk >> 8;       // 0:Q 1:K 2:V
  int rem = blk & 255;
  int b = rem >> 5;
  int rt = (rem >> 1) & 15;
  int et = rem & 1;

  const float* X = (mat == 0) ? query : (mat == 1 ? key : value);
  const float* bias = (mat == 0) ? bq : (mat == 1 ? bk : bv);
  const char* Wsrc = (const char*)(Wb + mat * HID * HID + et * 128 * HID);

#pragma unroll
  for (int i = 0; i < 8; i++) {
    int c = i * 512 + tid;
    int e = c >> 5;
    int glo = e * 512 + (((c & 31) ^ (e & 7)) << 4);
    __builtin_amdgcn_global_load_lds(
        (const __attribute__((address_space(1))) unsigned int*)(Wsrc + glo),
        (__attribute__((address_space(3))) unsigned int*)(wl + c * 16), 16, 0, 0);
  }

  int row_a = rt * 128 + wave * 16 + lr;
  const float* xrow = X + ((size_t)(b * SQL + row_a)) * HID;
  bf16x8 af[8];
#pragma unroll
  for (int s = 0; s < 8; s++) {
    const float4* p = (const float4*)(xrow + s * 32 + lg * 8);
    float4 x0 = p[0], x1 = p[1];
    bf16x8 a;
    a[0] = (short)f2bf(x0.x); a[1] = (short)f2bf(x0.y); a[2] = (short)f2bf(x0.z); a[3] = (short)f2bf(x0.w);
    a[4] = (short)f2bf(x1.x); a[5] = (short)f2bf(x1.y); a[6] = (short)f2bf(x1.z); a[7] = (short)f2bf(x1.w);
    af[s] = a;
  }
  __syncthreads();

  int row_c = rt * 128 + wave * 16 + lg * 4;
#pragma unroll
  for (int eo = 0; eo < 8; eo++) {
    f32x4 acc = (f32x4){0.f, 0.f, 0.f, 0.f};
    int eL = eo * 16 + lr;
#pragma unroll
    for (int sl = 0; sl < 8; sl++) {
      bf16x8 bfr = *(const bf16x8*)(wl + eL * 512 + (((sl * 4 + lg) ^ (eL & 7)) << 4));
      acc = __builtin_amdgcn_mfma_f32_16x16x32_bf16(af[sl], bfr, acc, 0, 0, 0);
    }
    int e = et * 128 + eo * 16 + lr;
    float bv_ = bias[e];
    if (mat < 2) {
      unsigned short* dst = (mat == 0 ? Qb : Kb) + (size_t)(b * SQL) * HID;
#pragma unroll
      for (int i = 0; i < 4; i++)
        dst[(size_t)(row_c + i) * HID + e] = f2bf(acc[i] + bv_);
    } else {
      ushort4 v;
      v.x = f2bf(acc[0] + bv_); v.y = f2bf(acc[1] + bv_);
      v.z = f2bf(acc[2] + bv_); v.w = f2bf(acc[3] + bv_);
      *(ushort4*)(Vtb + ((size_t)(b * HID + e)) * SKV + row_c) = v;
    }
  }
}

// ---------- A: flash attention, counted-vmcnt pipeline, 8 waves, KVB=64 ----------
__global__ __launch_bounds__(512, 2) void attn_kernel(
    const unsigned short* __restrict__ Qb, const unsigned short* __restrict__ Kb,
    const unsigned short* __restrict__ Vtb, unsigned short* __restrict__ Op,
    float* __restrict__ Ml) {
  extern __shared__ char smem[];  // K0[32K] K1[32K] V0[32K] V1[32K] = 128KB
  int tid = threadIdx.x;
  int wave = tid >> 6, lane = tid & 63, l31 = lane & 31, h = lane >> 5;
  // XCD-grouped: each XCD gets one batch (all its splits/q-tiles) -> K/V L2-resident
  int L = (blockIdx.x & 7) * 32 + (blockIdx.x >> 3);
  int b = L >> 5, sp = (L >> 3) & 3, qt = L & 7;
  int q0 = qt * 256 + wave * 32;

  const char* Kc0 = (const char*)Kb + ((size_t)b * SKV + (size_t)sp * KPB) * (HID * 2);
  const char* Vc0 = (const char*)Vtb + (size_t)b * HID * SKV * 2 + (size_t)sp * KPB * 2;

  // stage one 64-key tile: K 32KB (64 rows x 512B, chunk c at slot cs = c^(key&31)),
  //                        V 32KB (256 d-rows x 128B, chunk c at slot cs = c^(d&7))
  auto stage = [&](int t, char* kb, char* vb) {
    const char* Ks = Kc0 + t * (KVB * HID * 2);
    const char* Vs = Vc0 + t * (KVB * 2);
#pragma unroll
    for (int i = 0; i < 4; i++) {
      int g = i * 512 + tid;          // 0..2047
      int ky = g >> 5, cs = g & 31;
      __builtin_amdgcn_global_load_lds(
          (const __attribute__((address_space(1))) unsigned int*)(Ks + ky * 512 + ((cs ^ (ky & 31)) << 4)),
          (__attribute__((address_space(3))) unsigned int*)(kb + g * 16), 16, 0, 0);
    }
#pragma unroll
    for (int i = 0; i < 4; i++) {
      int g = i * 512 + tid;          // 0..2047
      int d = g >> 3, cs = g & 7;
      __builtin_amdgcn_global_load_lds(
          (const __attribute__((address_space(1))) unsigned int*)(Vs + (size_t)d * (SKV * 2) + ((cs ^ (d & 7)) << 4)),
          (__attribute__((address_space(3))) unsigned int*)(vb + g * 16), 16, 0, 0);
    }
  };

  // Q fragments (B-operand), 16 slices: lane holds Q[q=l31][s*16 + h*8 ..+7]
  bf16x8 qf[16];
  {
    const unsigned short* qrow = Qb + ((size_t)(b * SQL + q0 + l31)) * HID + h * 8;
#pragma unroll
    for (int s = 0; s < 16; s++) qf[s] = *(const bf16x8*)(qrow + s * 16);
  }

  f32x16 acc[8];
#pragma unroll
  for (int dt = 0; dt < 8; dt++)
#pragma unroll
    for (int j = 0; j < 16; j++) acc[dt][j] = 0.f;

  float m = -1e30f, lsum = 0.f;
  const float kC = 1.44269504088896341f / 11.3137084989847604f;  // log2(e)/sqrt(128)

  // one 32-key substep: QK^T(swapped) -> online softmax -> T12 -> PV
  auto substep = [&](const char* kb, const char* vb, int kt) {
    f32x16 p;
#pragma unroll
    for (int j = 0; j < 16; j++) p[j] = 0.f;
#pragma unroll
    for (int s = 0; s < 16; s++) {
      bf16x8 kf = *(const bf16x8*)(kb + (kt * 32 + l31) * 512 + (((2 * s + h) ^ l31) << 4));
      p = __builtin_amdgcn_mfma_f32_32x32x16_bf16(kf, qf[s], p, 0, 0, 0);
    }

    float tmax = p[0];
#pragma unroll
    for (int j = 1; j < 16; j++) tmax = fmaxf(tmax, p[j]);
    tmax = fmaxf(tmax, __shfl_xor(tmax, 32, 64));
    float msc = tmax * kC;
    if (!__all(msc <= m + 8.0f)) {
      float mn = fmaxf(m, msc);
      float al = exp2f(m - mn);
      lsum *= al;
      m = mn;
#pragma unroll
      for (int r = 0; r < 16; r++) {
        int qp = (r & 3) + 8 * (r >> 2) + 4 * h;
        float ar = __shfl(al, qp, 64);
#pragma unroll
        for (int dt = 0; dt < 8; dt++) acc[dt][r] *= ar;
      }
    }
#pragma unroll
    for (int j = 0; j < 16; j++) p[j] = exp2f(fmaf(p[j], kC, -m));
    float ts = 0.f;
#pragma unroll
    for (int j = 0; j < 16; j++) ts += p[j];
    ts += __shfl_xor(ts, 32, 64);
    lsum += ts;

#pragma unroll
    for (int k2 = 0; k2 < 2; k2++) {
      unsigned P0, P1, P2, P3;
      asm("v_cvt_pk_bf16_f32 %0, %1, %2" : "=v"(P0) : "v"(p[k2 * 8 + 0]), "v"(p[k2 * 8 + 1]));
      asm("v_cvt_pk_bf16_f32 %0, %1, %2" : "=v"(P1) : "v"(p[k2 * 8 + 2]), "v"(p[k2 * 8 + 3]));
      asm("v_cvt_pk_bf16_f32 %0, %1, %2" : "=v"(P2) : "v"(p[k2 * 8 + 4]), "v"(p[k2 * 8 + 5]));
      asm("v_cvt_pk_bf16_f32 %0, %1, %2" : "=v"(P3) : "v"(p[k2 * 8 + 6]), "v"(p[k2 * 8 + 7]));
      asm("v_permlane32_swap_b32 %0, %1" : "+v"(P0), "+v"(P2));
      asm("v_permlane32_swap_b32 %0, %1" : "+v"(P1), "+v"(P3));
      union { unsigned u[4]; bf16x8 v; } pa;
      pa.u[0] = P0; pa.u[1] = P1; pa.u[2] = P2; pa.u[3] = P3;
      int c = kt * 4 + k2 * 2 + h;    // V chunk index (8 keys each)
#pragma unroll
      for (int dt = 0; dt < 8; dt++) {
        bf16x8 vf = *(const bf16x8*)(vb + (dt * 32 + l31) * 128 + (((c ^ (l31 & 7)) & 7) << 4));
        acc[dt] = __builtin_amdgcn_mfma_f32_32x32x16_bf16(pa.v, vf, acc[dt], 0, 0, 0);
      }
    }
  };

  stage(0, smem, smem + 65536);
  for (int t = 0; t < NT; t++) {
    const char* kb = smem + (t & 1) * 32768;
    const char* vb = smem + 65536 + (t & 1) * 32768;
    if (t + 1 < NT) {
      stage(t + 1, smem + ((t + 1) & 1) * 32768, smem + 65536 + ((t + 1) & 1) * 32768);
      asm volatile("s_waitcnt vmcnt(8)" ::: "memory");   // tile t landed; t+1 stays in flight
    } else {
      asm volatile("s_waitcnt vmcnt(0)" ::: "memory");
    }
    __builtin_amdgcn_s_barrier();                        // all waves' tile-t portions landed
    __builtin_amdgcn_sched_barrier(0);                   // don't hoist ds_reads above this
    substep(kb, vb, 0);
    substep(kb, vb, 1);
    __builtin_amdgcn_s_barrier();                        // all done reading tile t
  }

  // epilogue: (m,l) + normalized f16 partial O
  if (h == 0) {
    float2 ml; ml.x = m; ml.y = lsum;
    *(float2*)(Ml + ((size_t)sp * NROW + (size_t)b * SQL + q0 + l31) * 2) = ml;
  }
#pragma unroll
  for (int r = 0; r < 16; r++) {
    int qp = (r & 3) + 8 * (r >> 2) + 4 * h;
    float linv = 1.0f / __shfl(lsum, qp, 64);
    size_t row = (size_t)b * SQL + q0 + qp;
#pragma unroll
    for (int dt = 0; dt < 8; dt++) {
      union { _Float16 hf; unsigned short u; } cv;
      cv.hf = (_Float16)(acc[dt][r] * linv);
      Op[((size_t)sp * NROW + row) * HID + dt * 32 + l31] = cv.u;
    }
  }
}

// ---------- C: combine split partials ----------
__global__ __launch_bounds__(256) void comb_kernel(const unsigned short* __restrict__ Op,
                                                   const float* __restrict__ Ml,
                                                   float* __restrict__ out) {
  int idx = blockIdx.x * 256 + threadIdx.x;
  int row = idx >> 6;
  int d0 = (idx & 63) << 2;
  float mv[SPLIT], lv[SPLIT];
#pragma unroll
  for (int s = 0; s < SPLIT; s++) {
    float2 ml = *(const float2*)(Ml + ((size_t)s * NROW + row) * 2);
    mv[s] = ml.x; lv[s] = ml.y;
  }
  float M = mv[0];
#pragma unroll
  for (int s = 1; s < SPLIT; s++) M = fmaxf(M, mv[s]);
  float W = 0.f, w[SPLIT];
#pragma unroll
  for (int s = 0; s < SPLIT; s++) { w[s] = lv[s] * exp2f(mv[s] - M); W += w[s]; }
  float wi = 1.0f / W;
  float o0 = 0.f, o1 = 0.f, o2 = 0.f, o3 = 0.f;
#pragma unroll
  for (int s = 0; s < SPLIT; s++) {
    ushort4 u = *(const ushort4*)(Op + ((size_t)s * NROW + row) * HID + d0);
    union { unsigned short us; _Float16 hf; } c0, c1, c2, c3;
    c0.us = u.x; c1.us = u.y; c2.us = u.z; c3.us = u.w;
    o0 += w[s] * (float)c0.hf; o1 += w[s] * (float)c1.hf;
    o2 += w[s] * (float)c2.hf; o3 += w[s] * (float)c3.hf;
  }
  float4 res; res.x = o0 * wi; res.y = o1 * wi; res.z = o2 * wi; res.w = o3 * wi;
  *(float4*)(out + (size_t)row * HID + d0) = res;
}

extern "C" void kernel_launch(void* const* d_in, const int* in_sizes, int n_in,
                              void* d_out, int out_size, void* d_ws, size_t ws_size,
                              hipStream_t stream) {
  const float* query = (const float*)d_in[0];
  const float* key   = (const float*)d_in[1];
  const float* value = (const float*)d_in[2];
  const float* Wq = (const float*)d_in[3];
  const float* bq = (const float*)d_in[4];
  const float* Wk = (const float*)d_in[5];
  const float* bk = (const float*)d_in[6];
  const float* Wv = (const float*)d_in[7];
  const float* bv = (const float*)d_in[8];

  char* ws = (char*)d_ws;
  unsigned short* Wb  = (unsigned short*)ws;                        // 393216 B
  unsigned short* Qb  = (unsigned short*)(ws + 393216);
  unsigned short* Kb  = Qb + (size_t)NB * SQL * HID;
  unsigned short* Vtb = Kb + (size_t)NB * SKV * HID;                // [b][d][s]
  unsigned short* Op  = Vtb + (size_t)NB * HID * SKV;               // f16 partials
  float* Ml = (float*)(Op + (size_t)SPLIT * NROW * HID);            // (m,l)

  hipLaunchKernelGGL(wconv_kernel, dim3(768), dim3(256), 0, stream, Wq, Wk, Wv, Wb);
  hipLaunchKernelGGL(proj_kernel, dim3(768), dim3(512), 0, stream,
                     query, key, value, Wb, bq, bk, bv, Qb, Kb, Vtb);
  hipLaunchKernelGGL(attn_kernel, dim3(256), dim3(512), 131072, stream, Qb, Kb, Vtb, Op, Ml);
  hipLaunchKernelGGL(comb_kernel, dim3(4096), dim3(256), 0, stream, Op, Ml, (float*)d_out);
}